// Round 1
// baseline (339.759 us; speedup 1.0000x reference)
//
#include <hip/hip_runtime.h>
#include <hip/hip_bf16.h>

// MaskedRoIAlign: out[k,c,ph,pw] = mean over SR*SR bilinear samples of
// (features[b_k] * masks[k]) with torchvision RoIAlign edge handling.
// N=2, C=256, H=W=64, K=64, PH=PW=7, SCALE=0.25, SR=2. Output fp32.

constexpr int N_ = 2, C_ = 256, H_ = 64, W_ = 64;
constexpr int K_ = 64, PH_ = 7, PW_ = 7, SR_ = 2;
constexpr float SCALE_ = 0.25f;

// Block: 256 threads = 4 channels x 64 lanes; lane -> output bin (49 used).
// One block per (box, channel-group-of-4) so a wave's 16 corner gathers all
// land in one (k,c) slice's small footprint -> L1 reuse, each HBM line ~once.
__global__ __launch_bounds__(256)
void masked_roialign_kernel(const float* __restrict__ features,
                            const float* __restrict__ boxes,
                            const float* __restrict__ masks,
                            float* __restrict__ out) {
    const int k  = blockIdx.x;            // box index, 0..63
    const int cg = blockIdx.y;            // channel group, 0..63
    const int t  = threadIdx.x;
    const int c   = cg * 4 + (t >> 6);    // channel
    const int bin = t & 63;               // output bin within 7x7
    if (bin >= PH_ * PW_) return;
    const int ph = bin / PW_;
    const int pw = bin - ph * PW_;

    // Box parameters (scalar per box; cheap to recompute per thread).
    const float* bx = boxes + k * 5;
    const int   b  = (int)bx[0];
    const float x1 = bx[1] * SCALE_;
    const float y1 = bx[2] * SCALE_;
    const float x2 = bx[3] * SCALE_;
    const float y2 = bx[4] * SCALE_;
    const float roi_w = fmaxf(x2 - x1, 1.0f);
    const float roi_h = fmaxf(y2 - y1, 1.0f);
    const float bin_w = roi_w * (1.0f / PW_);
    const float bin_h = roi_h * (1.0f / PH_);

    const float* __restrict__ f = features + ((size_t)b * C_ + c) * (H_ * W_);
    const float* __restrict__ m = masks    + ((size_t)k * C_ + c) * (H_ * W_);

    float acc = 0.0f;
#pragma unroll
    for (int iy = 0; iy < SR_; ++iy) {
        const float y  = y1 + ((float)ph + ((float)iy + 0.5f) * 0.5f) * bin_h;
        const bool  vy = (y >= -1.0f) && (y <= (float)H_);
        const float yc = fminf(fmaxf(y, 0.0f), (float)(H_ - 1));
        const int   yl = (int)yc;                  // yc >= 0 -> trunc == floor
        const int   yh = min(yl + 1, H_ - 1);
        const float ly = yc - (float)yl;
        const float hy = 1.0f - ly;
#pragma unroll
        for (int ix = 0; ix < SR_; ++ix) {
            const float x  = x1 + ((float)pw + ((float)ix + 0.5f) * 0.5f) * bin_w;
            const bool  vx = (x >= -1.0f) && (x <= (float)W_);
            const float xc = fminf(fmaxf(x, 0.0f), (float)(W_ - 1));
            const int   xl = (int)xc;
            const int   xh = min(xl + 1, W_ - 1);
            const float lx = xc - (float)xl;
            const float hx = 1.0f - lx;

            const int i00 = yl * W_ + xl, i01 = yl * W_ + xh;
            const int i10 = yh * W_ + xl, i11 = yh * W_ + xh;
            const float v00 = f[i00] * m[i00];
            const float v01 = f[i01] * m[i01];
            const float v10 = f[i10] * m[i10];
            const float v11 = f[i11] * m[i11];
            float val = hy * hx * v00 + hy * lx * v01
                      + ly * hx * v10 + ly * lx * v11;
            acc += (vy && vx) ? val : 0.0f;
        }
    }
    out[(((size_t)k * C_ + c) * PH_ + ph) * PW_ + pw] = acc * 0.25f;
}

extern "C" void kernel_launch(void* const* d_in, const int* in_sizes, int n_in,
                              void* d_out, int out_size, void* d_ws, size_t ws_size,
                              hipStream_t stream) {
    const float* features = (const float*)d_in[0];  // [2,256,64,64]
    const float* boxes    = (const float*)d_in[1];  // [64,5]
    const float* masks    = (const float*)d_in[2];  // [64,256,64,64]
    float* out            = (float*)d_out;          // [64,256,7,7]

    dim3 grid(K_, C_ / 4);   // 64 x 64 blocks
    dim3 block(256);
    masked_roialign_kernel<<<grid, block, 0, stream>>>(features, boxes, masks, out);
}